// Round 3
// baseline (841.857 us; speedup 1.0000x reference)
//
#include <hip/hip_runtime.h>
#include <stdint.h>

#define DEVI __device__ __forceinline__

typedef __attribute__((ext_vector_type(4))) float f32x4;
typedef __attribute__((ext_vector_type(8))) short bf16x8;
typedef __attribute__((ext_vector_type(4))) unsigned short u16x4;

DEVI unsigned short f2bf(float x) {
  union { float f; uint32_t u; } v; v.f = x;
  uint32_t r = v.u + 0x7FFFu + ((v.u >> 16) & 1u);  // RNE
  return (unsigned short)(r >> 16);
}
DEVI float bf2f(unsigned short h) {
  union { uint32_t u; float f; } v; v.u = ((uint32_t)h) << 16;
  return v.f;
}

DEVI void async16(const void* g, void* l) {
  __builtin_amdgcn_global_load_lds((__attribute__((address_space(1))) void*)g,
                                   (__attribute__((address_space(3))) void*)l,
                                   16, 0, 0);
}

// ---------------- P0: fp32 -> bf16 hi/lo split (a1 & a2 in one launch) -------
__global__ void k_split2(const float* __restrict__ x0, unsigned short* __restrict__ h0,
                         unsigned short* __restrict__ l0,
                         const float* __restrict__ x1, unsigned short* __restrict__ h1,
                         unsigned short* __restrict__ l1) {
  const long i = (long)blockIdx.x * 256 + threadIdx.x;
  const float* x = blockIdx.y ? x1 : x0;
  unsigned short* hh = blockIdx.y ? h1 : h0;
  unsigned short* ll = blockIdx.y ? l1 : l0;
  const f32x4 v = ((const f32x4*)x)[i];
  u16x4 H, L;
#pragma unroll
  for (int j = 0; j < 4; ++j) {
    H[j] = f2bf(v[j]);
    L[j] = f2bf(v[j] - bf2f(H[j]));
  }
  ((u16x4*)hh)[i] = H;
  ((u16x4*)ll)[i] = L;
}

__global__ void k_split(const float* __restrict__ x, unsigned short* __restrict__ hi,
                        unsigned short* __restrict__ lo, const long n4) {
  const long i = (long)blockIdx.x * 256 + threadIdx.x;
  if (i >= n4) return;
  const f32x4 v = ((const f32x4*)x)[i];
  u16x4 H, L;
#pragma unroll
  for (int j = 0; j < 4; ++j) {
    H[j] = f2bf(v[j]);
    L[j] = f2bf(v[j] - bf2f(H[j]));
  }
  ((u16x4*)hi)[i] = H;
  ((u16x4*)lo)[i] = L;
}

// ---------------- GEMM: C = A * B^T  (A: [M][Kd], B: [Nn][Kd], C: [M][Nn]) ----
// 128x128 tile, BK=64 (16 barriers for Kd=1024), 4 waves (2x2), 4x4 MFMA
// 16x16x32 tiles/wave, 2 k-steps per barrier. LDS chunk (kg,row) at ushort
// index (kg*128+row)*8 -> conflict-free ds_read_b128 frags, and contiguous in
// staging order (wave-uniform base + lane*16 for global_load_lds).
// STATS: epilogue computes per-block row (over cols) and col (over rows)
// online-softmax partials (m, sumexp) via in-register shuffle reductions.
template<bool SPLIT, bool OUTSPLIT, bool STATS, bool DUAL>
__global__ __launch_bounds__(256, 2)
void k_gemm_bt(const unsigned short* __restrict__ Ah, const unsigned short* __restrict__ Al,
               const unsigned short* __restrict__ Bh, const unsigned short* __restrict__ Bl,
               const float* __restrict__ bias,
               float* __restrict__ Cf, unsigned short* __restrict__ Ch,
               unsigned short* __restrict__ Cl,
               const unsigned short* __restrict__ Ax, const unsigned short* __restrict__ Bx,
               float* __restrict__ Cx,
               float* __restrict__ Rm, float* __restrict__ Rs,
               float* __restrict__ CmP, float* __restrict__ CsP,
               const int Kd, const int Nn,
               const long sA, const long sB, const long sC, const int lgx) {
  __shared__ __align__(16) unsigned short smem[SPLIT ? 32768 : 16384];
  const int tid  = threadIdx.x;
  const int lane = tid & 63;
  const int wave = tid >> 6;
  const int wm = wave >> 1, wn = wave & 1;
  const int m16 = lane & 15, quad = lane >> 4;

  // bijective decode (identity for (8,8,z) grids; spreads bx for P1's (128,8))
  const int lin = blockIdx.x + gridDim.x * (blockIdx.y + gridDim.y * blockIdx.z);
  const int by = (lin >> 3) & 7;
  const int u  = (lin & 7) | ((lin >> 6) << 3);
  const int bx = u & ((1 << lgx) - 1);
  int bz = u >> lgx;

  const unsigned short* Ahp = Ah;
  const unsigned short* Bhp = Bh;
  float* Cp = Cf;
  if (DUAL && bz >= 16) { Ahp = Ax; Bhp = Bx; Cp = Cx; bz -= 16; }

  const long aTile = (long)bz * sA + (long)bx * 128 * Kd;
  const long bTile = (long)bz * sB + (long)by * 128 * Kd;

  // staging: chunk t in [0,4): c = t*256 + tid ; row = tid&127 ; kg = 2t + (tid>>7)
  const int rs  = tid & 127;
  const int hcb = tid >> 7;
  const unsigned short* pAh = Ahp + aTile + (long)rs * Kd;
  const unsigned short* pBh = Bhp + bTile + (long)rs * Kd;
  const unsigned short* pAl = SPLIT ? (Al + aTile + (long)rs * Kd) : (const unsigned short*)0;
  const unsigned short* pBl = SPLIT ? (Bl + bTile + (long)rs * Kd) : (const unsigned short*)0;

  unsigned short* sAh = smem;
  unsigned short* sBh = smem + 8192;
  unsigned short* sAl = smem + (SPLIT ? 16384 : 0);
  unsigned short* sBl = smem + (SPLIT ? 24576 : 0);

  int off[4], lw[4];
#pragma unroll
  for (int t = 0; t < 4; ++t) {
    off[t] = (2 * t + hcb) * 8;
    lw[t]  = (t * 256 + wave * 64) * 8;
  }

  f32x4 acc[4][4];
#pragma unroll
  for (int i = 0; i < 4; ++i)
#pragma unroll
    for (int j = 0; j < 4; ++j) acc[i][j] = (f32x4){0.0f, 0.0f, 0.0f, 0.0f};

  const int arow = wm * 64 + m16;
  const int brow = wn * 64 + m16;
  const bf16x8* fAh = (const bf16x8*)sAh;
  const bf16x8* fBh = (const bf16x8*)sBh;
  const bf16x8* fAl = (const bf16x8*)sAl;
  const bf16x8* fBl = (const bf16x8*)sBl;

  for (int kt = 0; kt < Kd; kt += 64) {
    __syncthreads();
#pragma unroll
    for (int t = 0; t < 4; ++t) {
      async16(pAh + off[t] + kt, sAh + lw[t]);
      async16(pBh + off[t] + kt, sBh + lw[t]);
      if (SPLIT) {
        async16(pAl + off[t] + kt, sAl + lw[t]);
        async16(pBl + off[t] + kt, sBl + lw[t]);
      }
    }
    __syncthreads();

#pragma unroll
    for (int ks = 0; ks < 2; ++ks) {
      const int fb = (ks * 4 + quad) * 128;
      bf16x8 af[4], bb[4];
#pragma unroll
      for (int t = 0; t < 4; ++t) {
        af[t] = fAh[fb + arow + t * 16];
        bb[t] = fBh[fb + brow + t * 16];
      }
#pragma unroll
      for (int tm = 0; tm < 4; ++tm)
#pragma unroll
        for (int tn = 0; tn < 4; ++tn)
          acc[tm][tn] = __builtin_amdgcn_mfma_f32_16x16x32_bf16(af[tm], bb[tn], acc[tm][tn], 0, 0, 0);
      if (SPLIT) {
        bf16x8 xl[4];
#pragma unroll
        for (int t = 0; t < 4; ++t) xl[t] = fBl[fb + brow + t * 16];
#pragma unroll
        for (int tm = 0; tm < 4; ++tm)
#pragma unroll
          for (int tn = 0; tn < 4; ++tn)
            acc[tm][tn] = __builtin_amdgcn_mfma_f32_16x16x32_bf16(af[tm], xl[tn], acc[tm][tn], 0, 0, 0);
#pragma unroll
        for (int t = 0; t < 4; ++t) af[t] = fAl[fb + arow + t * 16];
#pragma unroll
        for (int tm = 0; tm < 4; ++tm)
#pragma unroll
          for (int tn = 0; tn < 4; ++tn)
            acc[tm][tn] = __builtin_amdgcn_mfma_f32_16x16x32_bf16(af[tm], bb[tn], acc[tm][tn], 0, 0, 0);
      }
    }
  }

  // epilogue: C/D layout col=lane&15, row=quad*4+i
  const long crow0 = (long)bx * 128 + wm * 64;
  const long ccol0 = (long)by * 128 + wn * 64;
  const long cBase = (long)bz * sC;
#pragma unroll
  for (int tn = 0; tn < 4; ++tn) {
    const long gcol = ccol0 + tn * 16 + m16;
    const float bv = OUTSPLIT ? bias[gcol] : 0.0f;
#pragma unroll
    for (int tm = 0; tm < 4; ++tm) {
#pragma unroll
      for (int i = 0; i < 4; ++i) {
        const long grow = crow0 + tm * 16 + quad * 4 + i;
        const long idx = cBase + grow * (long)Nn + gcol;
        const float val = acc[tm][tn][i] + bv;
        if (OUTSPLIT) {
          unsigned short h = f2bf(val);
          Ch[idx] = h;
          Cl[idx] = f2bf(val - bf2f(h));
        } else {
          Cp[idx] = val;
        }
      }
    }
  }

  if (STATS) {
    // ---- row partials (max & sumexp over this block's 128 cols) ----
    float rm[4][4], rsum[4][4];
#pragma unroll
    for (int tm = 0; tm < 4; ++tm)
#pragma unroll
      for (int i = 0; i < 4; ++i) {
        float m = acc[tm][0][i];
#pragma unroll
        for (int tn = 1; tn < 4; ++tn) m = fmaxf(m, acc[tm][tn][i]);
        rm[tm][i] = m;
      }
#pragma unroll
    for (int o = 1; o < 16; o <<= 1)
#pragma unroll
      for (int tm = 0; tm < 4; ++tm)
#pragma unroll
        for (int i = 0; i < 4; ++i)
          rm[tm][i] = fmaxf(rm[tm][i], __shfl_xor(rm[tm][i], o, 64));
#pragma unroll
    for (int tm = 0; tm < 4; ++tm)
#pragma unroll
      for (int i = 0; i < 4; ++i) {
        float s = 0.0f;
#pragma unroll
        for (int tn = 0; tn < 4; ++tn) s += __expf(acc[tm][tn][i] - rm[tm][i]);
        rsum[tm][i] = s;
      }
#pragma unroll
    for (int o = 1; o < 16; o <<= 1)
#pragma unroll
      for (int tm = 0; tm < 4; ++tm)
#pragma unroll
        for (int i = 0; i < 4; ++i)
          rsum[tm][i] += __shfl_xor(rsum[tm][i], o, 64);
    // ---- col partials (max & sumexp over this block's 128 rows) ----
    float cm[4], cs[4];
#pragma unroll
    for (int tn = 0; tn < 4; ++tn) {
      float m = acc[0][tn][0];
#pragma unroll
      for (int tm = 0; tm < 4; ++tm)
#pragma unroll
        for (int i = 0; i < 4; ++i) m = fmaxf(m, acc[tm][tn][i]);
      cm[tn] = m;
    }
#pragma unroll
    for (int o = 16; o < 64; o <<= 1)
#pragma unroll
      for (int tn = 0; tn < 4; ++tn) cm[tn] = fmaxf(cm[tn], __shfl_xor(cm[tn], o, 64));
#pragma unroll
    for (int tn = 0; tn < 4; ++tn) {
      float s = 0.0f;
#pragma unroll
      for (int tm = 0; tm < 4; ++tm)
#pragma unroll
        for (int i = 0; i < 4; ++i) s += __expf(acc[tm][tn][i] - cm[tn]);
      cs[tn] = s;
    }
#pragma unroll
    for (int o = 16; o < 64; o <<= 1)
#pragma unroll
      for (int tn = 0; tn < 4; ++tn) cs[tn] += __shfl_xor(cs[tn], o, 64);

    __syncthreads();
    float* sc = (float*)smem;   // [0:256) rowm, [256:512) rows, [512:768) colm, [768:1024) cols
    if (m16 == 0) {
#pragma unroll
      for (int tm = 0; tm < 4; ++tm)
#pragma unroll
        for (int i = 0; i < 4; ++i) {
          const int idx = (wm * 2 + wn) * 64 + tm * 16 + quad * 4 + i;
          sc[idx] = rm[tm][i];
          sc[256 + idx] = rsum[tm][i];
        }
    }
    if (quad == 0) {
#pragma unroll
      for (int tn = 0; tn < 4; ++tn) {
        const int idx = (wn * 2 + wm) * 64 + tn * 16 + m16;
        sc[512 + idx] = cm[tn];
        sc[768 + idx] = cs[tn];
      }
    }
    __syncthreads();
    if (tid < 128) {
      const int row = tid, wmi = row >> 6, r64 = row & 63;
      const float m0 = sc[(wmi * 2 + 0) * 64 + r64], s0 = sc[256 + (wmi * 2 + 0) * 64 + r64];
      const float m1v = sc[(wmi * 2 + 1) * 64 + r64], s1 = sc[256 + (wmi * 2 + 1) * 64 + r64];
      const float m = fmaxf(m0, m1v);
      const float s = s0 * __expf(m0 - m) + s1 * __expf(m1v - m);
      const long o = (((long)bz * 8 + by) << 10) + bx * 128 + row;
      Rm[o] = m; Rs[o] = s;
    } else {
      const int col = tid - 128, wni = col >> 6, c64 = col & 63;
      const float m0 = sc[512 + (wni * 2 + 0) * 64 + c64], s0 = sc[768 + (wni * 2 + 0) * 64 + c64];
      const float m1v = sc[512 + (wni * 2 + 1) * 64 + c64], s1 = sc[768 + (wni * 2 + 1) * 64 + c64];
      const float m = fmaxf(m0, m1v);
      const float s = s0 * __expf(m0 - m) + s1 * __expf(m1v - m);
      const long o = (((long)bz * 8 + bx) << 10) + by * 128 + col;
      CmP[o] = m; CsP[o] = s;
    }
  }
}

// ---------------- combine 8 partials -> m1,r1 (rows) / m2,r2 (cols) ----------
__global__ void k_statcomb(const float* __restrict__ Rm, const float* __restrict__ Rs,
                           const float* __restrict__ Cm, const float* __restrict__ Cs,
                           float* __restrict__ m1, float* __restrict__ r1,
                           float* __restrict__ m2, float* __restrict__ r2) {
  const int g = blockIdx.x * 256 + threadIdx.x;   // [0, 32768)
  const bool isCol = g >= 16384;
  const int rid = g & 16383;
  const int bz = rid >> 10, x = rid & 1023;
  const float* Pm = isCol ? Cm : Rm;
  const float* Ps = isCol ? Cs : Rs;
  float m = -3.4e38f, s = 0.0f;
#pragma unroll
  for (int j = 0; j < 8; ++j) {
    const long o = (((long)bz * 8 + j) << 10) + x;
    const float mj = Pm[o], sj = Ps[o];
    const float nm = fmaxf(m, mj);
    s = s * __expf(m - nm) + sj * __expf(mj - nm);
    m = nm;
  }
  if (isCol) { m2[rid] = m; r2[rid] = 1.0f / s; }
  else       { m1[rid] = m; r1[rid] = 1.0f / s; }
}

// ---------------- P5: A1 = softmax_k(S) bf16 ; A2T = softmax_l(S)^T bf16 -----
__global__ void k_agen(const float* __restrict__ S, const float* __restrict__ m1,
                       const float* __restrict__ r1, const float* __restrict__ m2,
                       const float* __restrict__ r2, unsigned short* __restrict__ A1,
                       unsigned short* __restrict__ A2T) {
  __shared__ float e2[64][65];
  const int n = blockIdx.z;
  const int k0 = blockIdx.x * 64, l0 = blockIdx.y * 64;
  const int q = threadIdx.x >> 4, p = threadIdx.x & 15;
  const long nb = (long)n << 20;
  const int kk = k0 + p * 4;
  const f32x4 mm2 = *(const f32x4*)(m2 + ((long)n << 10) + kk);
  const f32x4 rr2 = *(const f32x4*)(r2 + ((long)n << 10) + kk);
#pragma unroll
  for (int rr = 0; rr < 4; ++rr) {
    const int lrow = rr * 16 + q;
    const int l = l0 + lrow;
    const f32x4 s4 = *(const f32x4*)(S + nb + ((long)l << 10) + kk);
    const float mv = m1[((long)n << 10) + l], rv = r1[((long)n << 10) + l];
    u16x4 o;
#pragma unroll
    for (int j = 0; j < 4; ++j) {
      o[j] = f2bf(__expf(s4[j] - mv) * rv);
      e2[lrow][p * 4 + j] = __expf(s4[j] - mm2[j]) * rr2[j];
    }
    *(u16x4*)(A1 + nb + ((long)l << 10) + kk) = o;
  }
  __syncthreads();
#pragma unroll
  for (int rr = 0; rr < 4; ++rr) {
    const int krow = rr * 16 + q;
    u16x4 o;
#pragma unroll
    for (int j = 0; j < 4; ++j) o[j] = f2bf(e2[p * 4 + j][krow]);
    *(u16x4*)(A2T + nb + ((long)(k0 + krow) << 10) + (l0 + p * 4)) = o;
  }
}

// ---------------- transpose fp32 [n][r][c] -> bf16 [n][c][r], both inputs ----
__global__ void k_transpose2(const float* __restrict__ in0, unsigned short* __restrict__ out0,
                             const float* __restrict__ in1, unsigned short* __restrict__ out1) {
  __shared__ float t[64][65];
  const int zz = blockIdx.z;
  const int n = zz & 15;
  const float* in = (zz < 16) ? in0 : in1;
  unsigned short* out = (zz < 16) ? out0 : out1;
  const int c0 = blockIdx.x * 64, r0 = blockIdx.y * 64;
  const int q = threadIdx.x >> 4, p = threadIdx.x & 15;
  const long nb = (long)n << 20;
#pragma unroll
  for (int rr = 0; rr < 4; ++rr) {
    const int r = rr * 16 + q;
    const f32x4 v = *(const f32x4*)(in + nb + ((long)(r0 + r) << 10) + c0 + p * 4);
#pragma unroll
    for (int j = 0; j < 4; ++j) t[r][p * 4 + j] = v[j];
  }
  __syncthreads();
#pragma unroll
  for (int rr = 0; rr < 4; ++rr) {
    const int c = rr * 16 + q;
    u16x4 o;
#pragma unroll
    for (int j = 0; j < 4; ++j) o[j] = f2bf(t[p * 4 + j][c]);
    *(u16x4*)(out + nb + ((long)(c0 + c) << 10) + (r0 + p * 4)) = o;
  }
}

extern "C" void kernel_launch(void* const* d_in, const int* in_sizes, int n_in,
                              void* d_out, int out_size, void* d_ws, size_t ws_size,
                              hipStream_t stream) {
  const float* a1 = (const float*)d_in[0];
  const float* a2 = (const float*)d_in[1];
  const float* Gw = (const float*)d_in[2];
  const float* Gb = (const float*)d_in[3];
  float* out = (float*)d_out;
  char* ws = (char*)d_ws;
  const size_t MB = 1ull << 20;

  // phase-1 regions
  unsigned short* a1h  = (unsigned short*)(ws + 0 * MB);
  unsigned short* a1l  = (unsigned short*)(ws + 32 * MB);
  unsigned short* a2h  = (unsigned short*)(ws + 64 * MB);
  unsigned short* a2l  = (unsigned short*)(ws + 96 * MB);
  unsigned short* a2ph = (unsigned short*)(ws + 128 * MB);
  unsigned short* a2pl = (unsigned short*)(ws + 160 * MB);
  unsigned short* Gh   = (unsigned short*)(ws + 192 * MB);
  unsigned short* Gl   = (unsigned short*)(ws + 194 * MB);
  char* st = ws + 196 * MB;
  float* m1 = (float*)(st);
  float* r1 = (float*)(st + 64 * 1024);
  float* m2 = (float*)(st + 128 * 1024);
  float* r2 = (float*)(st + 192 * 1024);
  // stats partials live over the G region (G dead after P1)
  float* Rm = (float*)(ws + 192 * MB);
  float* Rs = (float*)(ws + 192 * MB + 512 * 1024);
  float* Cm = (float*)(ws + 193 * MB);
  float* Cs = (float*)(ws + 193 * MB + 512 * 1024);
  // lifetime-reused regions
  float* S            = (float*)(ws + 64 * MB);           // over a2h/a2l (dead after P1)
  unsigned short* A1  = (unsigned short*)(ws + 0 * MB);   // over a1h (dead after P2)
  unsigned short* A2T = (unsigned short*)(ws + 32 * MB);  // over a1l
  unsigned short* a2T = (unsigned short*)(ws + 128 * MB); // over a2ph (dead after P2)
  unsigned short* a1T = (unsigned short*)(ws + 160 * MB); // over a2pl

  const long B1M = 1048576;

  // P0: hi/lo splits (a1 & a2 fused; G separate)
  k_split2<<<dim3(16384, 2), 256, 0, stream>>>(a1, a1h, a1l, a2, a2h, a2l);
  k_split<<<1024, 256, 0, stream>>>(Gw, Gh, Gl, 262144);

  // P1: a2p[m][e] = a2[m][:] . Gw[e][:] + Gb[e]   (M=16384, split in/out)
  k_gemm_bt<true, true, false, false><<<dim3(128, 8, 1), 256, 0, stream>>>(
      a2h, a2l, Gh, Gl, Gb, nullptr, a2ph, a2pl, nullptr, nullptr, nullptr,
      nullptr, nullptr, nullptr, nullptr, 1024, 1024, 0, 0, 0, 7);

  // P2: S[n][l][k] = a1[n][l][:] . a2p[n][k][:]  (fp32 out + stats partials)
  k_gemm_bt<true, false, true, false><<<dim3(8, 8, 16), 256, 0, stream>>>(
      a1h, a1l, a2ph, a2pl, nullptr, S, nullptr, nullptr, nullptr, nullptr, nullptr,
      Rm, Rs, Cm, Cs, 1024, 1024, B1M, B1M, B1M, 3);

  // combine partials -> m1,r1 (rows/l) and m2,r2 (cols/k)
  k_statcomb<<<128, 256, 0, stream>>>(Rm, Rs, Cm, Cs, m1, r1, m2, r2);

  // P5: A1 (softmax over k) and A2T (softmax over l, transposed) in bf16
  k_agen<<<dim3(16, 16, 16), 256, 0, stream>>>(S, m1, r1, m2, r2, A1, A2T);

  // bf16 transposes of the raw inputs (both in one launch)
  k_transpose2<<<dim3(16, 16, 32), 256, 0, stream>>>(a2, a2T, a1, a1T);

  // P6+P7 merged: z<16 -> M1 = A1 . a2T^T ; z>=16 -> M2 = A2T . a1T^T
  k_gemm_bt<false, false, false, true><<<dim3(8, 8, 32), 256, 0, stream>>>(
      A1, nullptr, a2T, nullptr, nullptr, out, nullptr, nullptr,
      A2T, a1T, out + 16777216, nullptr, nullptr, nullptr, nullptr,
      1024, 1024, B1M, B1M, B1M, 3);
}